// Round 2
// baseline (676.378 us; speedup 1.0000x reference)
//
#include <hip/hip_runtime.h>
#include <stdint.h>

#define N_NODES 20000
#define E_EDGES 320000
#define H_DIM 128
#define A_DIM 512
#define NEMB_N 400
#define K_SEL 80000u
#define NB1 16384
#define NB2 16384
#define CAND_MAX 8192
#define LO_F (-128.0f)
#define SCALE1 (16384.0f / 160.0f)   /* bins over [-128, 32) */

struct SelState {
    int b1; unsigned cum1; unsigned r1;
    int b2; unsigned cum2; unsigned r2;
    unsigned long long T; unsigned need_eq;
};

// ---------------- threefry2x32 (JAX, 20 rounds) ----------------
__device__ __forceinline__ uint32_t rotl32(uint32_t x, int r) {
    return (x << r) | (x >> (32 - r));
}

__device__ __forceinline__ void threefry2x32(uint32_t k0, uint32_t k1,
                                             uint32_t& x0, uint32_t& x1) {
    uint32_t ks0 = k0, ks1 = k1, ks2 = k0 ^ k1 ^ 0x1BD11BDAu;
    x0 += ks0; x1 += ks1;
    // group 0: rotations {13,15,26,6}
    x0 += x1; x1 = rotl32(x1, 13); x1 ^= x0;
    x0 += x1; x1 = rotl32(x1, 15); x1 ^= x0;
    x0 += x1; x1 = rotl32(x1, 26); x1 ^= x0;
    x0 += x1; x1 = rotl32(x1, 6);  x1 ^= x0;
    x0 += ks1; x1 += ks2 + 1u;
    // group 1: {17,29,16,24}
    x0 += x1; x1 = rotl32(x1, 17); x1 ^= x0;
    x0 += x1; x1 = rotl32(x1, 29); x1 ^= x0;
    x0 += x1; x1 = rotl32(x1, 16); x1 ^= x0;
    x0 += x1; x1 = rotl32(x1, 24); x1 ^= x0;
    x0 += ks2; x1 += ks0 + 2u;
    // group 2: {13,15,26,6}
    x0 += x1; x1 = rotl32(x1, 13); x1 ^= x0;
    x0 += x1; x1 = rotl32(x1, 15); x1 ^= x0;
    x0 += x1; x1 = rotl32(x1, 26); x1 ^= x0;
    x0 += x1; x1 = rotl32(x1, 6);  x1 ^= x0;
    x0 += ks0; x1 += ks1 + 3u;
    // group 3: {17,29,16,24}
    x0 += x1; x1 = rotl32(x1, 17); x1 ^= x0;
    x0 += x1; x1 = rotl32(x1, 29); x1 ^= x0;
    x0 += x1; x1 = rotl32(x1, 16); x1 ^= x0;
    x0 += x1; x1 = rotl32(x1, 24); x1 ^= x0;
    x0 += ks1; x1 += ks2 + 4u;
    // group 4: {13,15,26,6}
    x0 += x1; x1 = rotl32(x1, 13); x1 ^= x0;
    x0 += x1; x1 = rotl32(x1, 15); x1 ^= x0;
    x0 += x1; x1 = rotl32(x1, 26); x1 ^= x0;
    x0 += x1; x1 = rotl32(x1, 6);  x1 ^= x0;
    x0 += ks2; x1 += ks0 + 5u;
}

// JAX partitionable threefry 32-bit path: counter=(hi=0, lo=e), key=(0,42),
// output bits = out0 ^ out1  (prng.py::_threefry_random_bits_partitionable)
__global__ __launch_bounds__(256) void k_rand(float* __restrict__ u) {
    int e = blockIdx.x * 256 + threadIdx.x;
    if (e >= E_EDGES) return;
    uint32_t x0 = 0u, x1 = (uint32_t)e;
    threefry2x32(0u, 42u, x0, x1);
    uint32_t bits = x0 ^ x1;
    uint32_t fb = (bits >> 9) | 0x3f800000u;
    u[e] = __uint_as_float(fb) - 1.0f;
}

// ---------- fused node precompute (f64): xl, v_node, q_node ----------
__global__ __launch_bounds__(128) void k_node(
    const float* __restrict__ x, const float* __restrict__ aerial,
    const float* __restrict__ Wlin, const float* __restrict__ blin,
    const float* __restrict__ Wq, const float* __restrict__ bq,
    const float* __restrict__ Wv, const float* __restrict__ bv,
    float* __restrict__ xl32, double* __restrict__ q64, double* __restrict__ v64) {
    __shared__ float  xin[8][H_DIM];
    __shared__ double xs[8][H_DIM];
    __shared__ float  aer[8][A_DIM];
    const int j = threadIdx.x;
    const int n0 = blockIdx.x * 8;
#pragma unroll
    for (int m = 0; m < 8; ++m) xin[m][j] = x[(size_t)(n0 + m) * H_DIM + j];
#pragma unroll
    for (int m = 0; m < 8; ++m)
#pragma unroll
        for (int c = 0; c < 4; ++c)
            aer[m][c * H_DIM + j] = aerial[(size_t)(n0 + m) * A_DIM + c * H_DIM + j];
    __syncthreads();
    // xl = x @ Wlin + blin
    double acc[8];
    {
        double bj = (double)blin[j];
#pragma unroll
        for (int m = 0; m < 8; ++m) acc[m] = bj;
        for (int k = 0; k < H_DIM; ++k) {
            double w = (double)Wlin[k * H_DIM + j];
#pragma unroll
            for (int m = 0; m < 8; ++m) acc[m] = fma((double)xin[m][k], w, acc[m]);
        }
    }
#pragma unroll
    for (int m = 0; m < 8; ++m) {
        xs[m][j] = acc[m];
        xl32[(size_t)(n0 + m) * H_DIM + j] = (float)acc[m];
    }
    __syncthreads();
    // v_node = xl @ Wv + bv
    {
        double bj = (double)bv[j];
        double av[8];
#pragma unroll
        for (int m = 0; m < 8; ++m) av[m] = bj;
        for (int k = 0; k < H_DIM; ++k) {
            double w = (double)Wv[k * H_DIM + j];
#pragma unroll
            for (int m = 0; m < 8; ++m) av[m] = fma(xs[m][k], w, av[m]);
        }
#pragma unroll
        for (int m = 0; m < 8; ++m) v64[(size_t)(n0 + m) * H_DIM + j] = av[m];
    }
    // q_node = xl @ Wq[0:128] + aerial @ Wq[128:640] + bq
    {
        double bj = (double)bq[j];
        double aq[8];
#pragma unroll
        for (int m = 0; m < 8; ++m) aq[m] = bj;
        for (int k = 0; k < H_DIM; ++k) {
            double w = (double)Wq[k * H_DIM + j];
#pragma unroll
            for (int m = 0; m < 8; ++m) aq[m] = fma(xs[m][k], w, aq[m]);
        }
        for (int k = 0; k < A_DIM; ++k) {
            double w = (double)Wq[(size_t)(H_DIM + k) * H_DIM + j];
#pragma unroll
            for (int m = 0; m < 8; ++m) aq[m] = fma((double)aer[m][k], w, aq[m]);
        }
#pragma unroll
        for (int m = 0; m < 8; ++m) q64[(size_t)(n0 + m) * H_DIM + j] = aq[m];
    }
}

// dist_q = dist_table @ Wq[640:768]   (no bias; bq folded into q_node)
__global__ __launch_bounds__(128) void k_dist(
    const float* __restrict__ dtab, const float* __restrict__ Wq,
    double* __restrict__ dq64) {
    __shared__ float ds[8][H_DIM];
    const int j = threadIdx.x;
    const int n0 = blockIdx.x * 8;
#pragma unroll
    for (int m = 0; m < 8; ++m) ds[m][j] = dtab[(size_t)(n0 + m) * H_DIM + j];
    __syncthreads();
    double acc[8];
#pragma unroll
    for (int m = 0; m < 8; ++m) acc[m] = 0.0;
    for (int k = 0; k < H_DIM; ++k) {
        double w = (double)Wq[(size_t)(H_DIM + A_DIM + k) * H_DIM + j];
#pragma unroll
        for (int m = 0; m < 8; ++m) acc[m] = fma((double)ds[m][k], w, acc[m]);
    }
#pragma unroll
    for (int m = 0; m < 8; ++m) dq64[(size_t)(n0 + m) * H_DIM + j] = acc[m];
}

// ---------- per-edge score (wave per edge), f64 norm + f32 gumbel ----------
__global__ __launch_bounds__(256) void k_score(
    const int* __restrict__ ei, const int* __restrict__ dist,
    const double* __restrict__ q64, const double* __restrict__ v64,
    const double* __restrict__ dq64, const float* __restrict__ u,
    unsigned long long* __restrict__ keys, float* __restrict__ s32o) {
    const int wid = threadIdx.x >> 6, lane = threadIdx.x & 63;
    const int e = blockIdx.x * 4 + wid;
    const int s = ei[e], t = ei[E_EDGES + e];
    const int db = dist[e] / 50;
    const double* qp = q64 + (size_t)s * H_DIM;
    const double* vp = v64 + (size_t)t * H_DIM;
    const double* dp = dq64 + (size_t)db * H_DIM;
    const int h = lane * 2;
    double d0 = qp[h] + dp[h] - vp[h];
    double d1 = qp[h + 1] + dp[h + 1] - vp[h + 1];
    double ss = fma(d0, d0, d1 * d1);
#pragma unroll
    for (int o = 32; o > 0; o >>= 1) ss += __shfl_xor(ss, o, 64);
    if (lane == 0) {
        double nrm = sqrt(ss);
        float uu = u[e];
        float a = -logf(uu + 1e-20f);
        float g = -logf(a + 1e-20f);
        double score = (double)g - nrm;
        long long ib = __double_as_longlong(score);
        unsigned long long ub = (unsigned long long)ib;
        ub = (ib < 0) ? ~ub : (ub | 0x8000000000000000ull);
        keys[e] = ub;
        s32o[e] = (float)score;
    }
}

__device__ __forceinline__ int bin1_of(float s) {
    float t = (s - LO_F) * SCALE1;
    int b = (int)t;
    return min(max(b, 0), NB1 - 1);
}
__device__ __forceinline__ int bin2_of(float s, int b1) {
    float t = (s - LO_F) * SCALE1;
    float frac = t - (float)b1;
    int b = (int)(frac * (float)NB2);
    return min(max(b, 0), NB2 - 1);
}

__global__ __launch_bounds__(256) void k_hist1(const float* __restrict__ s32,
                                               unsigned* __restrict__ hist1) {
    int e = blockIdx.x * 256 + threadIdx.x;
    if (e >= E_EDGES) return;
    atomicAdd(&hist1[bin1_of(s32[e])], 1u);
}

__global__ __launch_bounds__(256) void k_hist2(const float* __restrict__ s32,
                                               const SelState* __restrict__ st,
                                               unsigned* __restrict__ hist2) {
    int e = blockIdx.x * 256 + threadIdx.x;
    if (e >= E_EDGES) return;
    float s = s32[e];
    int b1 = bin1_of(s);
    if (b1 != st->b1) return;
    atomicAdd(&hist2[bin2_of(s, b1)], 1u);
}

// descending scan over 16384 bins to locate the bin holding the target rank
__global__ __launch_bounds__(256) void k_scan(const unsigned* __restrict__ hist,
                                              SelState* st, int phase) {
    __shared__ unsigned csum[256];
    __shared__ unsigned bins[64];
    __shared__ int selc;
    __shared__ unsigned cumbase;
    const int t = threadIdx.x;
    const unsigned target = (phase == 1) ? K_SEL : st->r1;
    unsigned s = 0;
    for (int i = 0; i < 64; ++i) s += hist[t * 64 + i];
    csum[t] = s;
    __syncthreads();
    if (t == 0) {
        unsigned cum = 0; int c = 255;
        for (; c >= 0; --c) {
            if (cum + csum[c] >= target) break;
            cum += csum[c];
        }
        selc = c; cumbase = cum;
    }
    __syncthreads();
    if (t < 64) bins[t] = hist[selc * 64 + t];
    __syncthreads();
    if (t == 0) {
        unsigned cum = cumbase; int b = -1;
        for (int i = 63; i >= 0; --i) {
            if (cum + bins[i] >= target) { b = selc * 64 + i; break; }
            cum += bins[i];
        }
        unsigned r = target - cum;
        if (phase == 1) { st->b1 = b; st->cum1 = cum; st->r1 = r; }
        else           { st->b2 = b; st->cum2 = cum; st->r2 = r; }
    }
}

__global__ __launch_bounds__(256) void k_collect(
    const float* __restrict__ s32, const unsigned long long* __restrict__ keys,
    const SelState* __restrict__ st, unsigned long long* __restrict__ cand,
    unsigned* __restrict__ cnt) {
    int e = blockIdx.x * 256 + threadIdx.x;
    if (e >= E_EDGES) return;
    float s = s32[e];
    int b1 = bin1_of(s);
    if (b1 != st->b1) return;
    if (bin2_of(s, b1) != st->b2) return;
    unsigned p = atomicAdd(cnt, 1u);
    if (p < CAND_MAX) cand[p] = keys[e];
}

// exact r2-th largest key among the (few) candidates
__global__ __launch_bounds__(256) void k_thresh(
    const unsigned long long* __restrict__ cand, const unsigned* __restrict__ cnt,
    SelState* st) {
    int c = (int)min(*cnt, (unsigned)CAND_MAX);
    unsigned r2 = st->r2;
    for (int i = threadIdx.x; i < c; i += blockDim.x) {
        unsigned long long ki = cand[i];
        unsigned g = 0, eq = 0;
        for (int j = 0; j < c; ++j) {
            unsigned long long kj = cand[j];
            g += (kj > ki); eq += (kj == ki);
        }
        if (g < r2 && r2 <= g + eq) { st->T = ki; st->need_eq = r2 - g; }
    }
}

// wave per edge: apply selection, scatter xl[src] into msg[tgt] + deg
__global__ __launch_bounds__(256) void k_scatter(
    const int* __restrict__ ei, const unsigned long long* __restrict__ keys,
    const float* __restrict__ s32, const SelState* __restrict__ st,
    unsigned* __restrict__ eqClaim, const float* __restrict__ xl32,
    float* __restrict__ msg, float* __restrict__ deg) {
    const int wid = threadIdx.x >> 6, lane = threadIdx.x & 63;
    const int e = blockIdx.x * 4 + wid;
    unsigned long long key = keys[e];
    float s = s32[e];
    int b1 = bin1_of(s);
    int sel;
    int B1 = st->b1;
    if (b1 > B1) sel = 1;
    else if (b1 < B1) sel = 0;
    else {
        int b2 = bin2_of(s, b1);
        int B2 = st->b2;
        if (b2 > B2) sel = 1;
        else if (b2 < B2) sel = 0;
        else {
            unsigned long long T = st->T;
            if (key > T) sel = 1;
            else if (key < T) sel = 0;
            else {
                int ok = 0;
                if (lane == 0) {
                    unsigned p = atomicAdd(eqClaim, 1u);
                    ok = (p < st->need_eq);
                }
                sel = __shfl(ok, 0, 64);
            }
        }
    }
    if (sel) {
        int sidx = ei[e], tidx = ei[E_EDGES + e];
        const float* xp = xl32 + (size_t)sidx * H_DIM;
        float* mp = msg + (size_t)tidx * H_DIM;
        const int h = lane * 2;
        atomicAdd(&mp[h], xp[h]);
        atomicAdd(&mp[h + 1], xp[h + 1]);
        if (lane == 0) atomicAdd(&deg[tidx], 1.0f);
    }
}

// out = (msg/max(deg,1)) @ Wl + bl + xl @ Wr
__global__ __launch_bounds__(128) void k_out(
    const float* __restrict__ msg, const float* __restrict__ deg,
    const float* __restrict__ xl32, const float* __restrict__ Wl,
    const float* __restrict__ bl, const float* __restrict__ Wr,
    float* __restrict__ out) {
    __shared__ float ax[8][H_DIM];
    __shared__ float xx[8][H_DIM];
    const int j = threadIdx.x;
    const int n0 = blockIdx.x * 8;
#pragma unroll
    for (int m = 0; m < 8; ++m) {
        float d = fmaxf(deg[n0 + m], 1.0f);
        ax[m][j] = msg[(size_t)(n0 + m) * H_DIM + j] / d;
        xx[m][j] = xl32[(size_t)(n0 + m) * H_DIM + j];
    }
    __syncthreads();
    float acc[8];
    float bj = bl[j];
#pragma unroll
    for (int m = 0; m < 8; ++m) acc[m] = bj;
    for (int k = 0; k < H_DIM; ++k) {
        float wl = Wl[k * H_DIM + j];
        float wr = Wr[k * H_DIM + j];
#pragma unroll
        for (int m = 0; m < 8; ++m) {
            acc[m] = fmaf(ax[m][k], wl, acc[m]);
            acc[m] = fmaf(xx[m][k], wr, acc[m]);
        }
    }
#pragma unroll
    for (int m = 0; m < 8; ++m) out[(size_t)(n0 + m) * H_DIM + j] = acc[m];
}

extern "C" void kernel_launch(void* const* d_in, const int* in_sizes, int n_in,
                              void* d_out, int out_size, void* d_ws, size_t ws_size,
                              hipStream_t stream) {
    const float* x      = (const float*)d_in[0];
    const int*   ei     = (const int*)d_in[1];
    const int*   dist   = (const int*)d_in[2];
    const float* aerial = (const float*)d_in[3];
    const float* Wlin   = (const float*)d_in[4];
    const float* blin   = (const float*)d_in[5];
    const float* Wq     = (const float*)d_in[6];
    const float* bq     = (const float*)d_in[7];
    const float* Wv     = (const float*)d_in[8];
    const float* bv     = (const float*)d_in[9];
    const float* dtab   = (const float*)d_in[10];
    const float* Wl     = (const float*)d_in[11];
    const float* bl     = (const float*)d_in[12];
    const float* Wr     = (const float*)d_in[13];
    float* out = (float*)d_out;

    char* ws = (char*)d_ws;
    size_t off = 0;
    auto alloc = [&](size_t bytes) -> void* {
        void* p = ws + off;
        off += (bytes + 255) & ~(size_t)255;
        return p;
    };
    double* q64  = (double*)alloc((size_t)N_NODES * H_DIM * 8);
    double* v64  = (double*)alloc((size_t)N_NODES * H_DIM * 8);
    double* dq64 = (double*)alloc((size_t)NEMB_N * H_DIM * 8);
    unsigned long long* keys = (unsigned long long*)alloc((size_t)E_EDGES * 8);
    float* xl32 = (float*)alloc((size_t)N_NODES * H_DIM * 4);
    float* urnd = (float*)alloc((size_t)E_EDGES * 4);
    float* s32  = (float*)alloc((size_t)E_EDGES * 4);
    char* zbase = ws + off;
    float* msg  = (float*)alloc((size_t)N_NODES * H_DIM * 4);
    float* deg  = (float*)alloc((size_t)N_NODES * 4);
    unsigned* hist1 = (unsigned*)alloc((size_t)NB1 * 4);
    unsigned* hist2 = (unsigned*)alloc((size_t)NB2 * 4);
    unsigned long long* cand = (unsigned long long*)alloc((size_t)CAND_MAX * 8);
    unsigned* counters = (unsigned*)alloc(256);   // [0]=candCount, [1]=eqClaim
    SelState* st = (SelState*)alloc(256);
    size_t zlen = (size_t)((ws + off) - zbase);

    hipMemsetAsync(zbase, 0, zlen, stream);

    k_node<<<N_NODES / 8, 128, 0, stream>>>(x, aerial, Wlin, blin, Wq, bq, Wv, bv,
                                            xl32, q64, v64);
    k_dist<<<NEMB_N / 8, 128, 0, stream>>>(dtab, Wq, dq64);
    k_rand<<<(E_EDGES + 255) / 256, 256, 0, stream>>>(urnd);
    k_score<<<E_EDGES / 4, 256, 0, stream>>>(ei, dist, q64, v64, dq64, urnd, keys, s32);
    k_hist1<<<(E_EDGES + 255) / 256, 256, 0, stream>>>(s32, hist1);
    k_scan<<<1, 256, 0, stream>>>(hist1, st, 1);
    k_hist2<<<(E_EDGES + 255) / 256, 256, 0, stream>>>(s32, st, hist2);
    k_scan<<<1, 256, 0, stream>>>(hist2, st, 2);
    k_collect<<<(E_EDGES + 255) / 256, 256, 0, stream>>>(s32, keys, st, cand, &counters[0]);
    k_thresh<<<1, 256, 0, stream>>>(cand, &counters[0], st);
    k_scatter<<<E_EDGES / 4, 256, 0, stream>>>(ei, keys, s32, st, &counters[1],
                                               xl32, msg, deg);
    k_out<<<N_NODES / 8, 128, 0, stream>>>(msg, deg, xl32, Wl, bl, Wr, out);
}

// Round 3
// 487.838 us; speedup vs baseline: 1.3865x; 1.3865x over previous
//
#include <hip/hip_runtime.h>
#include <stdint.h>

#define N_NODES 20000
#define E_EDGES 320000
#define H_DIM 128
#define A_DIM 512
#define NEMB_N 400
#define K_SEL 80000u
#define NB1 16384
#define NB2 16384
#define CAND_MAX 8192
#define LO_F (-128.0f)
#define SCALE1 (16384.0f / 160.0f)   /* bins over [-128, 32) */

struct SelState {
    int b1; unsigned cum1; unsigned r1;
    int b2; unsigned cum2; unsigned r2;
    unsigned long long T;
};

// ---------------- threefry2x32 (JAX, 20 rounds) ----------------
__device__ __forceinline__ uint32_t rotl32(uint32_t x, int r) {
    return (x << r) | (x >> (32 - r));
}

__device__ __forceinline__ void threefry2x32(uint32_t k0, uint32_t k1,
                                             uint32_t& x0, uint32_t& x1) {
    uint32_t ks0 = k0, ks1 = k1, ks2 = k0 ^ k1 ^ 0x1BD11BDAu;
    x0 += ks0; x1 += ks1;
    x0 += x1; x1 = rotl32(x1, 13); x1 ^= x0;
    x0 += x1; x1 = rotl32(x1, 15); x1 ^= x0;
    x0 += x1; x1 = rotl32(x1, 26); x1 ^= x0;
    x0 += x1; x1 = rotl32(x1, 6);  x1 ^= x0;
    x0 += ks1; x1 += ks2 + 1u;
    x0 += x1; x1 = rotl32(x1, 17); x1 ^= x0;
    x0 += x1; x1 = rotl32(x1, 29); x1 ^= x0;
    x0 += x1; x1 = rotl32(x1, 16); x1 ^= x0;
    x0 += x1; x1 = rotl32(x1, 24); x1 ^= x0;
    x0 += ks2; x1 += ks0 + 2u;
    x0 += x1; x1 = rotl32(x1, 13); x1 ^= x0;
    x0 += x1; x1 = rotl32(x1, 15); x1 ^= x0;
    x0 += x1; x1 = rotl32(x1, 26); x1 ^= x0;
    x0 += x1; x1 = rotl32(x1, 6);  x1 ^= x0;
    x0 += ks0; x1 += ks1 + 3u;
    x0 += x1; x1 = rotl32(x1, 17); x1 ^= x0;
    x0 += x1; x1 = rotl32(x1, 29); x1 ^= x0;
    x0 += x1; x1 = rotl32(x1, 16); x1 ^= x0;
    x0 += x1; x1 = rotl32(x1, 24); x1 ^= x0;
    x0 += ks1; x1 += ks2 + 4u;
    x0 += x1; x1 = rotl32(x1, 13); x1 ^= x0;
    x0 += x1; x1 = rotl32(x1, 15); x1 ^= x0;
    x0 += x1; x1 = rotl32(x1, 26); x1 ^= x0;
    x0 += x1; x1 = rotl32(x1, 6);  x1 ^= x0;
    x0 += ks2; x1 += ks0 + 5u;
}

// JAX partitionable threefry: counter=(0,e), key=(0,42), bits = out0 ^ out1
__global__ __launch_bounds__(256) void k_rand(float* __restrict__ u) {
    int e = blockIdx.x * 256 + threadIdx.x;
    if (e >= E_EDGES) return;
    uint32_t x0 = 0u, x1 = (uint32_t)e;
    threefry2x32(0u, 42u, x0, x1);
    uint32_t bits = x0 ^ x1;
    uint32_t fb = (bits >> 9) | 0x3f800000u;
    u[e] = __uint_as_float(fb) - 1.0f;
}

// ---------- fused node precompute (f32): xl, v_node, q_node ----------
// LDS holds transposed operand tiles [k][m] so the inner loop reads the
// 8-node operand as two broadcast float4s (ds_read_b128, conflict-free).
__global__ __launch_bounds__(128) void k_node(
    const float* __restrict__ x, const float* __restrict__ aerial,
    const float* __restrict__ Wlin, const float* __restrict__ blin,
    const float* __restrict__ Wq, const float* __restrict__ bq,
    const float* __restrict__ Wv, const float* __restrict__ bv,
    float* __restrict__ xl32, float* __restrict__ q32, float* __restrict__ v32) {
    __shared__ float xinT[H_DIM][8];   // [k][m]
    __shared__ float xsT[H_DIM][8];
    __shared__ float aerT[A_DIM][8];
    const int j = threadIdx.x;
    const int n0 = blockIdx.x * 8;
#pragma unroll
    for (int m = 0; m < 8; ++m) xinT[j][m] = x[(size_t)(n0 + m) * H_DIM + j];
#pragma unroll
    for (int m = 0; m < 8; ++m)
#pragma unroll
        for (int c = 0; c < 4; ++c)
            aerT[c * H_DIM + j][m] = aerial[(size_t)(n0 + m) * A_DIM + c * H_DIM + j];
    __syncthreads();
    // xl = x @ Wlin + blin
    float acc[8];
    {
        float bj = blin[j];
#pragma unroll
        for (int m = 0; m < 8; ++m) acc[m] = bj;
        for (int k = 0; k < H_DIM; ++k) {
            float w = Wlin[k * H_DIM + j];
            const float4* xp = (const float4*)&xinT[k][0];
            float4 a0 = xp[0], a1 = xp[1];
            acc[0] = fmaf(a0.x, w, acc[0]); acc[1] = fmaf(a0.y, w, acc[1]);
            acc[2] = fmaf(a0.z, w, acc[2]); acc[3] = fmaf(a0.w, w, acc[3]);
            acc[4] = fmaf(a1.x, w, acc[4]); acc[5] = fmaf(a1.y, w, acc[5]);
            acc[6] = fmaf(a1.z, w, acc[6]); acc[7] = fmaf(a1.w, w, acc[7]);
        }
    }
#pragma unroll
    for (int m = 0; m < 8; ++m) {
        xsT[j][m] = acc[m];
        xl32[(size_t)(n0 + m) * H_DIM + j] = acc[m];
    }
    __syncthreads();
    // v_node = xl @ Wv + bv
    {
        float bj = bv[j];
        float av[8];
#pragma unroll
        for (int m = 0; m < 8; ++m) av[m] = bj;
        for (int k = 0; k < H_DIM; ++k) {
            float w = Wv[k * H_DIM + j];
            const float4* xp = (const float4*)&xsT[k][0];
            float4 a0 = xp[0], a1 = xp[1];
            av[0] = fmaf(a0.x, w, av[0]); av[1] = fmaf(a0.y, w, av[1]);
            av[2] = fmaf(a0.z, w, av[2]); av[3] = fmaf(a0.w, w, av[3]);
            av[4] = fmaf(a1.x, w, av[4]); av[5] = fmaf(a1.y, w, av[5]);
            av[6] = fmaf(a1.z, w, av[6]); av[7] = fmaf(a1.w, w, av[7]);
        }
#pragma unroll
        for (int m = 0; m < 8; ++m) v32[(size_t)(n0 + m) * H_DIM + j] = av[m];
    }
    // q_node = xl @ Wq[0:128] + aerial @ Wq[128:640] + bq
    {
        float bj = bq[j];
        float aq[8];
#pragma unroll
        for (int m = 0; m < 8; ++m) aq[m] = bj;
        for (int k = 0; k < H_DIM; ++k) {
            float w = Wq[k * H_DIM + j];
            const float4* xp = (const float4*)&xsT[k][0];
            float4 a0 = xp[0], a1 = xp[1];
            aq[0] = fmaf(a0.x, w, aq[0]); aq[1] = fmaf(a0.y, w, aq[1]);
            aq[2] = fmaf(a0.z, w, aq[2]); aq[3] = fmaf(a0.w, w, aq[3]);
            aq[4] = fmaf(a1.x, w, aq[4]); aq[5] = fmaf(a1.y, w, aq[5]);
            aq[6] = fmaf(a1.z, w, aq[6]); aq[7] = fmaf(a1.w, w, aq[7]);
        }
        for (int k = 0; k < A_DIM; ++k) {
            float w = Wq[(size_t)(H_DIM + k) * H_DIM + j];
            const float4* xp = (const float4*)&aerT[k][0];
            float4 a0 = xp[0], a1 = xp[1];
            aq[0] = fmaf(a0.x, w, aq[0]); aq[1] = fmaf(a0.y, w, aq[1]);
            aq[2] = fmaf(a0.z, w, aq[2]); aq[3] = fmaf(a0.w, w, aq[3]);
            aq[4] = fmaf(a1.x, w, aq[4]); aq[5] = fmaf(a1.y, w, aq[5]);
            aq[6] = fmaf(a1.z, w, aq[6]); aq[7] = fmaf(a1.w, w, aq[7]);
        }
#pragma unroll
        for (int m = 0; m < 8; ++m) q32[(size_t)(n0 + m) * H_DIM + j] = aq[m];
    }
}

// dist_q = dist_table @ Wq[640:768]   (no bias; bq folded into q_node)
__global__ __launch_bounds__(128) void k_dist(
    const float* __restrict__ dtab, const float* __restrict__ Wq,
    float* __restrict__ dq32) {
    __shared__ float dsT[H_DIM][8];
    const int j = threadIdx.x;
    const int n0 = blockIdx.x * 8;
#pragma unroll
    for (int m = 0; m < 8; ++m) dsT[j][m] = dtab[(size_t)(n0 + m) * H_DIM + j];
    __syncthreads();
    float acc[8];
#pragma unroll
    for (int m = 0; m < 8; ++m) acc[m] = 0.0f;
    for (int k = 0; k < H_DIM; ++k) {
        float w = Wq[(size_t)(H_DIM + A_DIM + k) * H_DIM + j];
        const float4* xp = (const float4*)&dsT[k][0];
        float4 a0 = xp[0], a1 = xp[1];
        acc[0] = fmaf(a0.x, w, acc[0]); acc[1] = fmaf(a0.y, w, acc[1]);
        acc[2] = fmaf(a0.z, w, acc[2]); acc[3] = fmaf(a0.w, w, acc[3]);
        acc[4] = fmaf(a1.x, w, acc[4]); acc[5] = fmaf(a1.y, w, acc[5]);
        acc[6] = fmaf(a1.z, w, acc[6]); acc[7] = fmaf(a1.w, w, acc[7]);
    }
#pragma unroll
    for (int m = 0; m < 8; ++m) dq32[(size_t)(n0 + m) * H_DIM + j] = acc[m];
}

// ---------- per-edge score: 32 lanes per edge, float4 gathers ----------
__global__ __launch_bounds__(256) void k_score(
    const int* __restrict__ ei, const int* __restrict__ dist,
    const float* __restrict__ q32, const float* __restrict__ v32,
    const float* __restrict__ dq32, const float* __restrict__ u,
    unsigned long long* __restrict__ keys, float* __restrict__ s32o) {
    const int half = threadIdx.x >> 5, lane = threadIdx.x & 31;
    const int e = blockIdx.x * 8 + half;
    const int s = ei[e], t = ei[E_EDGES + e];
    const int db = dist[e] / 50;
    const float4* qp = (const float4*)(q32 + (size_t)s * H_DIM);
    const float4* vp = (const float4*)(v32 + (size_t)t * H_DIM);
    const float4* dp = (const float4*)(dq32 + (size_t)db * H_DIM);
    float4 q = qp[lane], v = vp[lane], d = dp[lane];
    float dx = q.x + d.x - v.x;
    float dy = q.y + d.y - v.y;
    float dz = q.z + d.z - v.z;
    float dw = q.w + d.w - v.w;
    float ss = fmaf(dx, dx, fmaf(dy, dy, fmaf(dz, dz, dw * dw)));
#pragma unroll
    for (int o = 16; o > 0; o >>= 1) ss += __shfl_xor(ss, o, 64);
    if (lane == 0) {
        float nrm = sqrtf(ss);
        float uu = u[e];
        float a = -logf(uu + 1e-20f);
        float g = -logf(a + 1e-20f);
        float score = g - nrm;
        int ib = __float_as_int(score);
        unsigned m32 = (ib < 0) ? ~(unsigned)ib : ((unsigned)ib | 0x80000000u);
        // unique key: score-ordered high bits, lower edge index wins ties
        keys[e] = ((unsigned long long)m32 << 32) | (unsigned)(0xFFFFFFFFu - (unsigned)e);
        s32o[e] = score;
    }
}

__device__ __forceinline__ int bin1_of(float s) {
    float t = (s - LO_F) * SCALE1;
    int b = (int)t;
    return min(max(b, 0), NB1 - 1);
}
__device__ __forceinline__ int bin2_of(float s, int b1) {
    float t = (s - LO_F) * SCALE1;
    float frac = t - (float)b1;
    int b = (int)(frac * (float)NB2);
    return min(max(b, 0), NB2 - 1);
}

__global__ __launch_bounds__(256) void k_hist1(const float* __restrict__ s32,
                                               unsigned* __restrict__ hist1) {
    int e = blockIdx.x * 256 + threadIdx.x;
    if (e >= E_EDGES) return;
    atomicAdd(&hist1[bin1_of(s32[e])], 1u);
}

__global__ __launch_bounds__(256) void k_hist2(const float* __restrict__ s32,
                                               const SelState* __restrict__ st,
                                               unsigned* __restrict__ hist2) {
    int e = blockIdx.x * 256 + threadIdx.x;
    if (e >= E_EDGES) return;
    float s = s32[e];
    int b1 = bin1_of(s);
    if (b1 != st->b1) return;
    atomicAdd(&hist2[bin2_of(s, b1)], 1u);
}

// descending scan over 16384 bins to locate the bin holding the target rank
__global__ __launch_bounds__(256) void k_scan(const unsigned* __restrict__ hist,
                                              SelState* st, int phase) {
    __shared__ unsigned csum[256];
    __shared__ unsigned bins[64];
    __shared__ int selc;
    __shared__ unsigned cumbase;
    const int t = threadIdx.x;
    const unsigned target = (phase == 1) ? K_SEL : st->r1;
    unsigned s = 0;
    for (int i = 0; i < 64; ++i) s += hist[t * 64 + i];
    csum[t] = s;
    __syncthreads();
    if (t == 0) {
        unsigned cum = 0; int c = 255;
        for (; c >= 0; --c) {
            if (cum + csum[c] >= target) break;
            cum += csum[c];
        }
        selc = c; cumbase = cum;
    }
    __syncthreads();
    if (t < 64) bins[t] = hist[selc * 64 + t];
    __syncthreads();
    if (t == 0) {
        unsigned cum = cumbase; int b = -1;
        for (int i = 63; i >= 0; --i) {
            if (cum + bins[i] >= target) { b = selc * 64 + i; break; }
            cum += bins[i];
        }
        unsigned r = target - cum;
        if (phase == 1) { st->b1 = b; st->cum1 = cum; st->r1 = r; }
        else           { st->b2 = b; st->cum2 = cum; st->r2 = r; }
    }
}

__global__ __launch_bounds__(256) void k_collect(
    const float* __restrict__ s32, const unsigned long long* __restrict__ keys,
    const SelState* __restrict__ st, unsigned long long* __restrict__ cand,
    unsigned* __restrict__ cnt) {
    int e = blockIdx.x * 256 + threadIdx.x;
    if (e >= E_EDGES) return;
    float s = s32[e];
    int b1 = bin1_of(s);
    if (b1 != st->b1) return;
    if (bin2_of(s, b1) != st->b2) return;
    unsigned p = atomicAdd(cnt, 1u);
    if (p < CAND_MAX) cand[p] = keys[e];
}

// T = r2-th largest key among candidates (keys are unique)
__global__ __launch_bounds__(256) void k_thresh(
    const unsigned long long* __restrict__ cand, const unsigned* __restrict__ cnt,
    SelState* st) {
    int c = (int)min(*cnt, (unsigned)CAND_MAX);
    unsigned r2 = st->r2;
    for (int i = threadIdx.x; i < c; i += blockDim.x) {
        unsigned long long ki = cand[i];
        unsigned g = 0;
        for (int j = 0; j < c; ++j) g += (cand[j] > ki);
        if (g == r2 - 1) st->T = ki;
    }
}

// wave per edge: key >= T selects; scatter xl[src] into msg[tgt] + deg
__global__ __launch_bounds__(256) void k_scatter(
    const int* __restrict__ ei, const unsigned long long* __restrict__ keys,
    const SelState* __restrict__ st, const float* __restrict__ xl32,
    float* __restrict__ msg, float* __restrict__ deg) {
    const int wid = threadIdx.x >> 6, lane = threadIdx.x & 63;
    const int e = blockIdx.x * 4 + wid;
    if (keys[e] >= st->T) {
        int sidx = ei[e], tidx = ei[E_EDGES + e];
        const float* xp = xl32 + (size_t)sidx * H_DIM;
        float* mp = msg + (size_t)tidx * H_DIM;
        const int h = lane * 2;
        atomicAdd(&mp[h], xp[h]);
        atomicAdd(&mp[h + 1], xp[h + 1]);
        if (lane == 0) atomicAdd(&deg[tidx], 1.0f);
    }
}

// out = (msg/max(deg,1)) @ Wl + bl + xl @ Wr
__global__ __launch_bounds__(128) void k_out(
    const float* __restrict__ msg, const float* __restrict__ deg,
    const float* __restrict__ xl32, const float* __restrict__ Wl,
    const float* __restrict__ bl, const float* __restrict__ Wr,
    float* __restrict__ out) {
    __shared__ float axT[H_DIM][8];
    __shared__ float xxT[H_DIM][8];
    const int j = threadIdx.x;
    const int n0 = blockIdx.x * 8;
#pragma unroll
    for (int m = 0; m < 8; ++m) {
        float d = fmaxf(deg[n0 + m], 1.0f);
        axT[j][m] = msg[(size_t)(n0 + m) * H_DIM + j] / d;
        xxT[j][m] = xl32[(size_t)(n0 + m) * H_DIM + j];
    }
    __syncthreads();
    float acc[8];
    float bj = bl[j];
#pragma unroll
    for (int m = 0; m < 8; ++m) acc[m] = bj;
    for (int k = 0; k < H_DIM; ++k) {
        float wl = Wl[k * H_DIM + j];
        float wr = Wr[k * H_DIM + j];
        const float4* ap = (const float4*)&axT[k][0];
        const float4* xp = (const float4*)&xxT[k][0];
        float4 a0 = ap[0], a1 = ap[1];
        float4 x0 = xp[0], x1 = xp[1];
        acc[0] = fmaf(a0.x, wl, fmaf(x0.x, wr, acc[0]));
        acc[1] = fmaf(a0.y, wl, fmaf(x0.y, wr, acc[1]));
        acc[2] = fmaf(a0.z, wl, fmaf(x0.z, wr, acc[2]));
        acc[3] = fmaf(a0.w, wl, fmaf(x0.w, wr, acc[3]));
        acc[4] = fmaf(a1.x, wl, fmaf(x1.x, wr, acc[4]));
        acc[5] = fmaf(a1.y, wl, fmaf(x1.y, wr, acc[5]));
        acc[6] = fmaf(a1.z, wl, fmaf(x1.z, wr, acc[6]));
        acc[7] = fmaf(a1.w, wl, fmaf(x1.w, wr, acc[7]));
    }
#pragma unroll
    for (int m = 0; m < 8; ++m) out[(size_t)(n0 + m) * H_DIM + j] = acc[m];
}

extern "C" void kernel_launch(void* const* d_in, const int* in_sizes, int n_in,
                              void* d_out, int out_size, void* d_ws, size_t ws_size,
                              hipStream_t stream) {
    const float* x      = (const float*)d_in[0];
    const int*   ei     = (const int*)d_in[1];
    const int*   dist   = (const int*)d_in[2];
    const float* aerial = (const float*)d_in[3];
    const float* Wlin   = (const float*)d_in[4];
    const float* blin   = (const float*)d_in[5];
    const float* Wq     = (const float*)d_in[6];
    const float* bq     = (const float*)d_in[7];
    const float* Wv     = (const float*)d_in[8];
    const float* bv     = (const float*)d_in[9];
    const float* dtab   = (const float*)d_in[10];
    const float* Wl     = (const float*)d_in[11];
    const float* bl     = (const float*)d_in[12];
    const float* Wr     = (const float*)d_in[13];
    float* out = (float*)d_out;

    char* ws = (char*)d_ws;
    size_t off = 0;
    auto alloc = [&](size_t bytes) -> void* {
        void* p = ws + off;
        off += (bytes + 255) & ~(size_t)255;
        return p;
    };
    float* q32  = (float*)alloc((size_t)N_NODES * H_DIM * 4);
    float* v32  = (float*)alloc((size_t)N_NODES * H_DIM * 4);
    float* dq32 = (float*)alloc((size_t)NEMB_N * H_DIM * 4);
    unsigned long long* keys = (unsigned long long*)alloc((size_t)E_EDGES * 8);
    float* xl32 = (float*)alloc((size_t)N_NODES * H_DIM * 4);
    float* urnd = (float*)alloc((size_t)E_EDGES * 4);
    float* s32  = (float*)alloc((size_t)E_EDGES * 4);
    char* zbase = ws + off;
    float* msg  = (float*)alloc((size_t)N_NODES * H_DIM * 4);
    float* deg  = (float*)alloc((size_t)N_NODES * 4);
    unsigned* hist1 = (unsigned*)alloc((size_t)NB1 * 4);
    unsigned* hist2 = (unsigned*)alloc((size_t)NB2 * 4);
    unsigned long long* cand = (unsigned long long*)alloc((size_t)CAND_MAX * 8);
    unsigned* counters = (unsigned*)alloc(256);   // [0]=candCount
    SelState* st = (SelState*)alloc(256);
    size_t zlen = (size_t)((ws + off) - zbase);

    hipMemsetAsync(zbase, 0, zlen, stream);

    k_node<<<N_NODES / 8, 128, 0, stream>>>(x, aerial, Wlin, blin, Wq, bq, Wv, bv,
                                            xl32, q32, v32);
    k_dist<<<NEMB_N / 8, 128, 0, stream>>>(dtab, Wq, dq32);
    k_rand<<<(E_EDGES + 255) / 256, 256, 0, stream>>>(urnd);
    k_score<<<E_EDGES / 8, 256, 0, stream>>>(ei, dist, q32, v32, dq32, urnd, keys, s32);
    k_hist1<<<(E_EDGES + 255) / 256, 256, 0, stream>>>(s32, hist1);
    k_scan<<<1, 256, 0, stream>>>(hist1, st, 1);
    k_hist2<<<(E_EDGES + 255) / 256, 256, 0, stream>>>(s32, st, hist2);
    k_scan<<<1, 256, 0, stream>>>(hist2, st, 2);
    k_collect<<<(E_EDGES + 255) / 256, 256, 0, stream>>>(s32, keys, st, cand, &counters[0]);
    k_thresh<<<1, 256, 0, stream>>>(cand, &counters[0], st);
    k_scatter<<<E_EDGES / 4, 256, 0, stream>>>(ei, keys, st, xl32, msg, deg);
    k_out<<<N_NODES / 8, 128, 0, stream>>>(msg, deg, xl32, Wl, bl, Wr, out);
}